// Round 1
// 766.727 us; speedup vs baseline: 1.0423x; 1.0423x over previous
//
#include <hip/hip_runtime.h>

#define Nn 100000
#define Ee 1600000
#define Pp 1000000
#define EPSf 1e-5f

typedef _Float16 f16x8 __attribute__((ext_vector_type(8)));
typedef _Float16 f16x4 __attribute__((ext_vector_type(4)));
typedef _Float16 f16x2 __attribute__((ext_vector_type(2)));
typedef float f32x4 __attribute__((ext_vector_type(4)));

__device__ __forceinline__ float4 ld4(const float* p) { return *(const float4*)p; }

// f16 weight arena offsets (elements)
#define oW1l 0        // 128x128
#define oW1r 16384    // 128x128
#define oW2l 32768    // 64x128
#define oW2r 40960    // 64x128
#define oW1a 49152    // 128x64   (pW1 cols 0..63)
#define oW1b 57344    // 128x64   (pW1 cols 64..127)
#define oW1c 65536    // 128x32   (pW1 cols 128..159)
#define oWe1 69632    // 64x32
#define oWe2 71680    // 32x64
#define oWp2 73728    // 64x128
#define W16_TOTAL 81920

#define BN_TOTAL 608

// ---------------- prep: f32 -> f16 weights/x + BN const folding ----------------
__global__ __launch_bounds__(256) void prep_kernel(
    const float* __restrict__ x,
    const float* __restrict__ s1Wl, const float* __restrict__ s1Wr,
    const float* __restrict__ s2Wl, const float* __restrict__ s2Wr,
    const float* __restrict__ pW1,  const float* __restrict__ eW1,
    const float* __restrict__ eW2,  const float* __restrict__ pW2,
    const float* __restrict__ eb1,
    const float* __restrict__ ebng, const float* __restrict__ ebnb,
    const float* __restrict__ ebnm, const float* __restrict__ ebnv,
    const float* __restrict__ eb2,
    const float* __restrict__ pb1,
    const float* __restrict__ p1g, const float* __restrict__ p1b,
    const float* __restrict__ p1m, const float* __restrict__ p1v,
    const float* __restrict__ pb2,
    const float* __restrict__ p2g, const float* __restrict__ p2b,
    const float* __restrict__ p2m, const float* __restrict__ p2v,
    const float* __restrict__ pW3,
    _Float16* __restrict__ w16, float* __restrict__ bnA,
    _Float16* __restrict__ x16) {
    int tid = blockIdx.x * 256 + threadIdx.x;
    if (tid < W16_TOTAL) {
        float v;
        if (tid < 16384)      v = s1Wl[tid];
        else if (tid < 32768) v = s1Wr[tid - 16384];
        else if (tid < 40960) v = s2Wl[tid - 32768];
        else if (tid < 49152) v = s2Wr[tid - 40960];
        else if (tid < 57344) { int l = tid - 49152; v = pW1[(l >> 6) * 160 + (l & 63)]; }
        else if (tid < 65536) { int l = tid - 57344; v = pW1[(l >> 6) * 160 + 64 + (l & 63)]; }
        else if (tid < 69632) { int l = tid - 65536; v = pW1[(l >> 5) * 160 + 128 + (l & 31)]; }
        else if (tid < 71680) v = eW1[tid - 69632];
        else if (tid < 73728) v = eW2[tid - 71680];
        else                  v = pW2[tid - 73728];
        w16[tid] = (_Float16)v;
    } else if (tid < W16_TOTAL + BN_TOTAL) {
        int b = tid - W16_TOTAL;
        float v;
        if (b < 64)       v = ebng[b] * rsqrtf(ebnv[b] + EPSf);
        else if (b < 128) { int c = b - 64;  float s = ebng[c] * rsqrtf(ebnv[c] + EPSf);
                            v = (eb1[c] - ebnm[c]) * s + ebnb[c]; }
        else if (b < 256) { int c = b - 128; v = p1g[c] * rsqrtf(p1v[c] + EPSf); }
        else if (b < 384) { int c = b - 256; float s = p1g[c] * rsqrtf(p1v[c] + EPSf);
                            v = (pb1[c] - p1m[c]) * s + p1b[c]; }
        else if (b < 448) { int c = b - 384; v = p2g[c] * rsqrtf(p2v[c] + EPSf); }
        else if (b < 512) { int c = b - 448; float s = p2g[c] * rsqrtf(p2v[c] + EPSf);
                            v = (pb2[c] - p2m[c]) * s + p2b[c]; }
        else if (b < 544) v = eb2[b - 512];
        else              v = pW3[b - 544];
        bnA[b] = v;
    }
    int stride = gridDim.x * 256;
    const int NV = Nn * 128 / 4;
    for (int i = tid; i < NV; i += stride) {
        float4 v = ((const float4*)x)[i];
        f16x4 h = {(_Float16)v.x, (_Float16)v.y, (_Float16)v.z, (_Float16)v.w};
        ((f16x4*)x16)[i] = h;
    }
}

// ---------------- CSR build ----------------
__global__ __launch_bounds__(256) void hist_kernel(const int* __restrict__ dst,
                                                   unsigned* __restrict__ deg) {
    int i = blockIdx.x * 256 + threadIdx.x;
    if (i < Ee) atomicAdd(&deg[dst[i]], 1u);
}

__global__ __launch_bounds__(1024) void scanA_kernel(const unsigned* __restrict__ deg,
                                                     unsigned* __restrict__ escan,
                                                     unsigned* __restrict__ bsum) {
    __shared__ unsigned s[1024];
    int t = threadIdx.x;
    int gid = blockIdx.x * 1024 + t;
    unsigned v = (gid < Nn) ? deg[gid] : 0u;
    s[t] = v;
    __syncthreads();
    for (int off = 1; off < 1024; off <<= 1) {
        unsigned u = (t >= off) ? s[t - off] : 0u;
        __syncthreads();
        s[t] += u;
        __syncthreads();
    }
    if (gid < Nn) escan[gid] = s[t] - v;
    if (t == 1023) bsum[blockIdx.x] = s[1023];
}

__global__ __launch_bounds__(128) void scanB_kernel(const unsigned* __restrict__ bsum,
                                                    unsigned* __restrict__ boff,
                                                    int nblk) {
    __shared__ unsigned s[128];
    int t = threadIdx.x;
    unsigned v = (t < nblk) ? bsum[t] : 0u;
    s[t] = v;
    __syncthreads();
    for (int off = 1; off < 128; off <<= 1) {
        unsigned u = (t >= off) ? s[t - off] : 0u;
        __syncthreads();
        s[t] += u;
        __syncthreads();
    }
    if (t < nblk) boff[t] = s[t] - v;
}

__global__ __launch_bounds__(1024) void scanC_kernel(const unsigned* __restrict__ escan,
                                                     const unsigned* __restrict__ boff,
                                                     int* __restrict__ rowptr,
                                                     int* __restrict__ cursor) {
    int t = threadIdx.x;
    int gid = blockIdx.x * 1024 + t;
    if (gid < Nn) {
        int v = (int)(escan[gid] + boff[blockIdx.x]);
        rowptr[gid] = v;
        cursor[gid] = v;
    }
    if (gid == 0) rowptr[Nn] = Ee;
}

__global__ __launch_bounds__(256) void scatter_kernel(const int* __restrict__ src,
                                                      const int* __restrict__ dst,
                                                      int* __restrict__ cursor,
                                                      int* __restrict__ elist) {
    int i = blockIdx.x * 256 + threadIdx.x;
    if (i < Ee) {
        int p = atomicAdd(&cursor[dst[i]], 1);
        elist[p] = src[i];
    }
}

// ---------------- f16 mean aggregation ----------------
template<int W>
__global__ __launch_bounds__(256, 8) void aggregate16_kernel(
    const _Float16* __restrict__ feat,
    const int* __restrict__ rowptr,
    const int* __restrict__ elist,
    _Float16* __restrict__ outp) {
    int node = (blockIdx.x * 256 + threadIdx.x) >> 6;
    int lane = threadIdx.x & 63;
    if (node >= Nn) return;
    constexpr int SEGS = W / 8;
    constexpr int RPI  = 64 / SEGS;
    const int r = lane / SEGS, c = lane % SEGS;
    int beg = rowptr[node], end = rowptr[node + 1];
    int n = end - beg;
    float acc[8];
#pragma unroll
    for (int k = 0; k < 8; ++k) acc[k] = 0.f;
    for (int c0 = 0; c0 < n; c0 += 64) {
        int m = min(64, n - c0);
        int se = (lane < m) ? elist[beg + c0 + lane] : 0;
        int iters = (m + RPI - 1) / RPI;
#pragma unroll 2
        for (int i = 0; i < iters; ++i) {
            int j = i * RPI + r;
            int s = __shfl(se, j);
            if (j < m) {
                f16x8 v = *(const f16x8*)(feat + (size_t)s * W + c * 8);
#pragma unroll
                for (int k = 0; k < 8; ++k) acc[k] += (float)v[k];
            }
        }
    }
#pragma unroll
    for (int k = 0; k < 8; ++k) {
#pragma unroll
        for (int off = SEGS; off < 64; off <<= 1)
            acc[k] += __shfl_xor(acc[k], off);
    }
    if (r == 0) {
        float inv = 1.0f / fmaxf((float)n, 1.0f);
        f16x8 o;
#pragma unroll
        for (int k = 0; k < 8; ++k) o[k] = (_Float16)(acc[k] * inv);
        *(f16x8*)(outp + (size_t)node * W + c * 8) = o;
    }
}

// ---------------- dense SAGE layer 1 via MFMA ----------------
__global__ __launch_bounds__(256) void dense1_kernel(
    const _Float16* __restrict__ A1, const _Float16* __restrict__ A2,
    const _Float16* __restrict__ W1, const _Float16* __restrict__ W2,
    const float* __restrict__ lb,
    const float* __restrict__ bng, const float* __restrict__ bnb,
    const float* __restrict__ bnm, const float* __restrict__ bnv,
    _Float16* __restrict__ out) {
    const int t = threadIdx.x;
    const int w = t >> 6, lane = t & 63;
    const int lrow = lane & 15, lq = lane >> 4;
    const int row0 = blockIdx.x * 64 + w * 16;
    const int ld = min(row0 + lrow, Nn - 1);

    f16x8 a1[4], a2[4];
#pragma unroll
    for (int i = 0; i < 4; ++i) {
        a1[i] = *(const f16x8*)(A1 + (size_t)ld * 128 + i * 32 + lq * 8);
        a2[i] = *(const f16x8*)(A2 + (size_t)ld * 128 + i * 32 + lq * 8);
    }
#pragma unroll
    for (int nt = 0; nt < 8; ++nt) {
        const _Float16* w1r = W1 + (size_t)(nt * 16 + lrow) * 128;
        const _Float16* w2r = W2 + (size_t)(nt * 16 + lrow) * 128;
        f32x4 c = {0.f, 0.f, 0.f, 0.f};
#pragma unroll
        for (int i = 0; i < 4; ++i) {
            c = __builtin_amdgcn_mfma_f32_16x16x32_f16(a1[i], *(const f16x8*)(w1r + i * 32 + lq * 8), c, 0, 0, 0);
            c = __builtin_amdgcn_mfma_f32_16x16x32_f16(a2[i], *(const f16x8*)(w2r + i * 32 + lq * 8), c, 0, 0, 0);
        }
        int cc = nt * 16 + lrow;
        float s = bng[cc] * rsqrtf(bnv[cc] + EPSf);
        float h = (lb[cc] - bnm[cc]) * s + bnb[cc];
#pragma unroll
        for (int r = 0; r < 4; ++r) {
            int gr = row0 + lq * 4 + r;
            if (gr < Nn)
                out[(size_t)gr * 128 + cc] = (_Float16)fmaxf(c[r] * s + h, 0.f);
        }
    }
}

// ---------------- y = h @ W2l^T ----------------
__global__ __launch_bounds__(256) void gemmY_kernel(
    const _Float16* __restrict__ A, const _Float16* __restrict__ W,
    _Float16* __restrict__ out) {
    const int t = threadIdx.x;
    const int w = t >> 6, lane = t & 63;
    const int lrow = lane & 15, lq = lane >> 4;
    const int row0 = blockIdx.x * 64 + w * 16;
    const int ld = min(row0 + lrow, Nn - 1);
    f16x8 a[4];
#pragma unroll
    for (int i = 0; i < 4; ++i)
        a[i] = *(const f16x8*)(A + (size_t)ld * 128 + i * 32 + lq * 8);
#pragma unroll
    for (int nt = 0; nt < 4; ++nt) {
        const _Float16* wr = W + (size_t)(nt * 16 + lrow) * 128;
        f32x4 c = {0.f, 0.f, 0.f, 0.f};
#pragma unroll
        for (int i = 0; i < 4; ++i)
            c = __builtin_amdgcn_mfma_f32_16x16x32_f16(a[i], *(const f16x8*)(wr + i * 32 + lq * 8), c, 0, 0, 0);
        int cc = nt * 16 + lrow;
#pragma unroll
        for (int r = 0; r < 4; ++r) {
            int gr = row0 + lq * 4 + r;
            if (gr < Nn) out[(size_t)gr * 64 + cc] = (_Float16)c[r];
        }
    }
}

// ---------------- z = aggY + h @ W2r^T + lb ----------------
__global__ __launch_bounds__(256) void dense2b_kernel(
    const _Float16* __restrict__ aggY, const _Float16* __restrict__ A2,
    const _Float16* __restrict__ W2, const float* __restrict__ lb,
    _Float16* __restrict__ out) {
    const int t = threadIdx.x;
    const int w = t >> 6, lane = t & 63;
    const int lrow = lane & 15, lq = lane >> 4;
    const int row0 = blockIdx.x * 64 + w * 16;
    const int ld = min(row0 + lrow, Nn - 1);
    f16x8 a[4];
#pragma unroll
    for (int i = 0; i < 4; ++i)
        a[i] = *(const f16x8*)(A2 + (size_t)ld * 128 + i * 32 + lq * 8);
#pragma unroll
    for (int nt = 0; nt < 4; ++nt) {
        const _Float16* wr = W2 + (size_t)(nt * 16 + lrow) * 128;
        f32x4 c = {0.f, 0.f, 0.f, 0.f};
#pragma unroll
        for (int i = 0; i < 4; ++i)
            c = __builtin_amdgcn_mfma_f32_16x16x32_f16(a[i], *(const f16x8*)(wr + i * 32 + lq * 8), c, 0, 0, 0);
        int cc = nt * 16 + lrow;
        float b = lb[cc];
#pragma unroll
        for (int r = 0; r < 4; ++r) {
            int gr = row0 + lq * 4 + r;
            if (gr < Nn) {
                float g = (float)aggY[(size_t)gr * 64 + cc];
                out[(size_t)gr * 64 + cc] = (_Float16)(c[r] + g + b);
            }
        }
    }
}

// ---------------- fused per-edge predictor: persistent, swapped-operand MFMA ----
// 512 threads = 8 waves x 16 edges = 128 edges/tile; 1 block/CU (103 KB LDS).
// Swapped mfma(W_frag, X_frag): lane holds 4 CONSECUTIVE channels of edge
// (lane&15) -> f16x4 ds_write_b64 epilogues, broadcast float4 BN reads, and
// the final 64-wide dot collapses to per-lane FMAs + 2 shfl_xor (no U2).
// P4 weights (W1a/W1b, 32 f16x8 = 128 VGPR) are hoisted to registers.
#define EPB 128
#define NT  ((Pp + EPB - 1) / EPB)     // 7813
#define EGRID 1024

#define oL_We1 0        // [64][40]   5120
#define oL_We2 5120     // [32][72]   4608
#define oL_W1c 9728     // [128][40]  10240
#define oL_Wp2 19968    // [64][136]  17408
#define oL_BN  37376    // 608 f32    2432
#define oL_E1  39808    // [128][72]  18432
#define oL_E2  58240    // [128][40]  10240
#define oL_ZU  68480    // [128][136] 34816
#define SMEM_BYTES 103296

__global__ __launch_bounds__(512, 2) void edge_kernel(
    const int* __restrict__ pe,
    const float* __restrict__ ef,
    const _Float16* __restrict__ z,      // [N,64]
    const _Float16* __restrict__ w16,
    const float* __restrict__ bnA,
    const float* __restrict__ pb3,
    float* __restrict__ out) {
    __shared__ __align__(16) unsigned char smem[SMEM_BYTES];
    _Float16* LWe1 = (_Float16*)(smem + oL_We1);
    _Float16* LWe2 = (_Float16*)(smem + oL_We2);
    _Float16* LW1c = (_Float16*)(smem + oL_W1c);
    _Float16* LWp2 = (_Float16*)(smem + oL_Wp2);
    float*    LBN  = (float*)(smem + oL_BN);
    _Float16* E1 = (_Float16*)(smem + oL_E1);
    _Float16* E2 = (_Float16*)(smem + oL_E2);
    _Float16* ZU = (_Float16*)(smem + oL_ZU);

    const float* bn1s = LBN;        const float* bn1h = LBN + 64;
    const float* bn2s = LBN + 128;  const float* bn2h = LBN + 256;
    const float* bn3s = LBN + 384;  const float* bn3h = LBN + 448;
    const float* eb2g = LBN + 512;  const float* wp3g = LBN + 544;

    const int t = threadIdx.x;
    const int lane = t & 63;
    const int w = t >> 6;          // 0..7
    const int m0 = w * 16;
    const int lrow = lane & 15;
    const int lq = lane >> 4;
    const int er = lane >> 3;      // gather: 8 rows per instruction
    const int seg = lane & 7;      // 16B segment within 128B z-row
    const float pb3v = pb3[0];

    // tile-data loader (registers only; issue before staging barrier is fine)
    auto load_tile = [&](int tl, f16x8* Ga, f16x8* Gb, float4& Ef0, float4& Ef1) -> bool {
        if (tl >= NT) return false;
        int e0 = tl * EPB + m0;
        if (e0 >= Pp) return false;
#pragma unroll
        for (int i = 0; i < 2; ++i) {
            int eg = e0 + i * 8 + er;
            int ai = pe[eg];
            int bi = pe[Pp + eg];
            Ga[i] = *(const f16x8*)(z + (size_t)ai * 64 + seg * 8);
            Gb[i] = *(const f16x8*)(z + (size_t)bi * 64 + seg * 8);
        }
        const float* src = ef + (size_t)(e0 + lrow) * 32 + lq * 8;
        Ef0 = ld4(src); Ef1 = ld4(src + 4);
        return true;
    };

    // ---- prefetch first tile (before staging: overlaps staging latency) ----
    int tile = blockIdx.x;
    f16x8 ga[2], gb[2]; float4 ef0, ef1;
    bool act = load_tile(tile, ga, gb, ef0, ef1);

    // ---- hoist P4 weight fragments into registers (loop-invariant) ----
    f16x8 wa0[8], wa1[8], wb0[8], wb1[8];
#pragma unroll
    for (int nt = 0; nt < 8; ++nt) {
        const _Float16* ra = w16 + oW1a + (size_t)(nt * 16 + lrow) * 64;
        const _Float16* rb = w16 + oW1b + (size_t)(nt * 16 + lrow) * 64;
        wa0[nt] = *(const f16x8*)(ra + lq * 8);
        wa1[nt] = *(const f16x8*)(ra + 32 + lq * 8);
        wb0[nt] = *(const f16x8*)(rb + lq * 8);
        wb1[nt] = *(const f16x8*)(rb + 32 + lq * 8);
    }

    // ---- stage remaining weights (padded) + BN consts into LDS ----
    for (int u = t; u < 256; u += 512) { int r = u >> 2, s = u & 3;
        *(f16x8*)(LWe1 + r * 40 + s * 8) = *(const f16x8*)(w16 + oWe1 + r * 32 + s * 8); }
    for (int u = t; u < 256; u += 512) { int r = u >> 3, s = u & 7;
        *(f16x8*)(LWe2 + r * 72 + s * 8) = *(const f16x8*)(w16 + oWe2 + r * 64 + s * 8); }
    for (int u = t; u < 512; u += 512) { int r = u >> 2, s = u & 3;
        *(f16x8*)(LW1c + r * 40 + s * 8) = *(const f16x8*)(w16 + oW1c + r * 32 + s * 8); }
    for (int u = t; u < 1024; u += 512) { int r = u >> 4, s = u & 15;
        *(f16x8*)(LWp2 + r * 136 + s * 8) = *(const f16x8*)(w16 + oWp2 + r * 128 + s * 8); }
    for (int u = t; u < BN_TOTAL; u += 512) LBN[u] = bnA[u];
    __syncthreads();

    // ---- persistent tile loop (no barriers inside; working LDS is wave-private) ----
    for (; tile < NT; tile += EGRID) {
        const int base = tile * EPB;

        // park current gathers into ZU (za cols 0..63, zb 64..127)
        if (act) {
#pragma unroll
            for (int i = 0; i < 2; ++i) {
                int e = m0 + i * 8 + er;
                *(f16x8*)(ZU + e * 136 + seg * 8) = ga[i];
                *(f16x8*)(ZU + e * 136 + 64 + seg * 8) = gb[i];
            }
        }
        // prefetch next tile (overlaps with this tile's compute)
        f16x8 nga[2], ngb[2]; float4 nef0, nef1;
        bool nact = load_tile(tile + EGRID, nga, ngb, nef0, nef1);

        if (act) {
            const int erow = m0 + lrow;
            // ---- P2: e1 = relu(bn(ef @ eW1^T)) -> E1[edge][64ch] ----
            {
                f16x8 b = {(_Float16)ef0.x, (_Float16)ef0.y, (_Float16)ef0.z, (_Float16)ef0.w,
                           (_Float16)ef1.x, (_Float16)ef1.y, (_Float16)ef1.z, (_Float16)ef1.w};
#pragma unroll
                for (int nt = 0; nt < 4; ++nt) {
                    f16x8 wf = *(const f16x8*)(LWe1 + (nt * 16 + lrow) * 40 + lq * 8);
                    f32x4 c = {0.f, 0.f, 0.f, 0.f};
                    c = __builtin_amdgcn_mfma_f32_16x16x32_f16(wf, b, c, 0, 0, 0);
                    int cb = nt * 16 + lq * 4;
                    float4 s = *(const float4*)(bn1s + cb);
                    float4 h = *(const float4*)(bn1h + cb);
                    f16x4 o;
                    o[0] = (_Float16)fmaxf(c[0] * s.x + h.x, 0.f);
                    o[1] = (_Float16)fmaxf(c[1] * s.y + h.y, 0.f);
                    o[2] = (_Float16)fmaxf(c[2] * s.z + h.z, 0.f);
                    o[3] = (_Float16)fmaxf(c[3] * s.w + h.w, 0.f);
                    *(f16x4*)(E1 + erow * 72 + cb) = o;
                }
            }
            // ---- P3: e2 = e1 @ eW2^T + eb2 -> E2[edge][32ch] ----
            {
                f16x8 a0 = *(const f16x8*)(E1 + erow * 72 + lq * 8);
                f16x8 a1 = *(const f16x8*)(E1 + erow * 72 + 32 + lq * 8);
#pragma unroll
                for (int nt = 0; nt < 2; ++nt) {
                    f16x8 b0 = *(const f16x8*)(LWe2 + (nt * 16 + lrow) * 72 + lq * 8);
                    f16x8 b1 = *(const f16x8*)(LWe2 + (nt * 16 + lrow) * 72 + 32 + lq * 8);
                    f32x4 c = {0.f, 0.f, 0.f, 0.f};
                    c = __builtin_amdgcn_mfma_f32_16x16x32_f16(b0, a0, c, 0, 0, 0);
                    c = __builtin_amdgcn_mfma_f32_16x16x32_f16(b1, a1, c, 0, 0, 0);
                    int cb = nt * 16 + lq * 4;
                    float4 bias = *(const float4*)(eb2g + cb);
                    f16x4 o;
                    o[0] = (_Float16)(c[0] + bias.x);
                    o[1] = (_Float16)(c[1] + bias.y);
                    o[2] = (_Float16)(c[2] + bias.z);
                    o[3] = (_Float16)(c[3] + bias.w);
                    *(f16x4*)(E2 + erow * 40 + cb) = o;
                }
            }
            // ---- P4: u1 = relu(bn1(za@W1a^T + zb@W1b^T + e2@W1c^T)) -> ZU[edge][128] ----
            {
                const int zr = erow * 136;
                f16x8 za0 = *(const f16x8*)(ZU + zr + lq * 8);
                f16x8 za1 = *(const f16x8*)(ZU + zr + 32 + lq * 8);
                f16x8 zb0 = *(const f16x8*)(ZU + zr + 64 + lq * 8);
                f16x8 zb1 = *(const f16x8*)(ZU + zr + 96 + lq * 8);
                f16x8 ae  = *(const f16x8*)(E2 + erow * 40 + lq * 8);
                __builtin_amdgcn_s_setprio(1);
#pragma unroll
                for (int nt = 0; nt < 8; ++nt) {
                    f16x8 wc = *(const f16x8*)(LW1c + (nt * 16 + lrow) * 40 + lq * 8);
                    f32x4 c = {0.f, 0.f, 0.f, 0.f};
                    c = __builtin_amdgcn_mfma_f32_16x16x32_f16(wa0[nt], za0, c, 0, 0, 0);
                    c = __builtin_amdgcn_mfma_f32_16x16x32_f16(wa1[nt], za1, c, 0, 0, 0);
                    c = __builtin_amdgcn_mfma_f32_16x16x32_f16(wb0[nt], zb0, c, 0, 0, 0);
                    c = __builtin_amdgcn_mfma_f32_16x16x32_f16(wb1[nt], zb1, c, 0, 0, 0);
                    c = __builtin_amdgcn_mfma_f32_16x16x32_f16(wc,      ae,  c, 0, 0, 0);
                    int cb = nt * 16 + lq * 4;
                    float4 s = *(const float4*)(bn2s + cb);
                    float4 h = *(const float4*)(bn2h + cb);
                    f16x4 o;
                    o[0] = (_Float16)fmaxf(c[0] * s.x + h.x, 0.f);
                    o[1] = (_Float16)fmaxf(c[1] * s.y + h.y, 0.f);
                    o[2] = (_Float16)fmaxf(c[2] * s.z + h.z, 0.f);
                    o[3] = (_Float16)fmaxf(c[3] * s.w + h.w, 0.f);
                    *(f16x4*)(ZU + zr + cb) = o;
                }
                __builtin_amdgcn_s_setprio(0);
            }
            // ---- P6+P7 fused: u2 = relu(bn2(u1 @ pW2^T)); out = u2 . pW3 + pb3 ----
            {
                const int zr = erow * 136;
                f16x8 a0 = *(const f16x8*)(ZU + zr + 0  + lq * 8);
                f16x8 a1 = *(const f16x8*)(ZU + zr + 32 + lq * 8);
                f16x8 a2 = *(const f16x8*)(ZU + zr + 64 + lq * 8);
                f16x8 a3 = *(const f16x8*)(ZU + zr + 96 + lq * 8);
                float acc = 0.f;
                __builtin_amdgcn_s_setprio(1);
#pragma unroll
                for (int nt = 0; nt < 4; ++nt) {
                    const _Float16* wr = LWp2 + (nt * 16 + lrow) * 136 + lq * 8;
                    f32x4 c = {0.f, 0.f, 0.f, 0.f};
                    c = __builtin_amdgcn_mfma_f32_16x16x32_f16(*(const f16x8*)(wr + 0),  a0, c, 0, 0, 0);
                    c = __builtin_amdgcn_mfma_f32_16x16x32_f16(*(const f16x8*)(wr + 32), a1, c, 0, 0, 0);
                    c = __builtin_amdgcn_mfma_f32_16x16x32_f16(*(const f16x8*)(wr + 64), a2, c, 0, 0, 0);
                    c = __builtin_amdgcn_mfma_f32_16x16x32_f16(*(const f16x8*)(wr + 96), a3, c, 0, 0, 0);
                    int cb = nt * 16 + lq * 4;
                    float4 s  = *(const float4*)(bn3s + cb);
                    float4 h  = *(const float4*)(bn3h + cb);
                    float4 w3 = *(const float4*)(wp3g + cb);
                    acc += fmaxf(c[0] * s.x + h.x, 0.f) * w3.x;
                    acc += fmaxf(c[1] * s.y + h.y, 0.f) * w3.y;
                    acc += fmaxf(c[2] * s.z + h.z, 0.f) * w3.z;
                    acc += fmaxf(c[3] * s.w + h.w, 0.f) * w3.w;
                }
                __builtin_amdgcn_s_setprio(0);
                acc += __shfl_xor(acc, 16);
                acc += __shfl_xor(acc, 32);
                if (lane < 16) out[base + m0 + lane] = acc + pb3v;
            }
        }
        // rotate prefetch -> current
        ga[0] = nga[0]; ga[1] = nga[1];
        gb[0] = ngb[0]; gb[1] = ngb[1];
        ef0 = nef0; ef1 = nef1;
        act = nact;
    }
}

// ---------------- launch ----------------
extern "C" void kernel_launch(void* const* d_in, const int* in_sizes, int n_in,
                              void* d_out, int out_size, void* d_ws, size_t ws_size,
                              hipStream_t stream) {
    const float* x    = (const float*)d_in[0];
    const int*   eidx = (const int*)d_in[1];
    const int*   pe   = (const int*)d_in[2];
    const float* ef   = (const float*)d_in[3];
    const float* s1Wl = (const float*)d_in[4];
    const float* s1bl = (const float*)d_in[5];
    const float* s1Wr = (const float*)d_in[6];
    const float* bn1g = (const float*)d_in[7];
    const float* bn1b = (const float*)d_in[8];
    const float* bn1m = (const float*)d_in[9];
    const float* bn1v = (const float*)d_in[10];
    const float* s2Wl = (const float*)d_in[11];
    const float* s2bl = (const float*)d_in[12];
    const float* s2Wr = (const float*)d_in[13];
    const float* eW1  = (const float*)d_in[14];
    const float* eb1  = (const float*)d_in[15];
    const float* ebng = (const float*)d_in[16];
    const float* ebnb = (const float*)d_in[17];
    const float* ebnm = (const float*)d_in[18];
    const float* ebnv = (const float*)d_in[19];
    const float* eW2  = (const float*)d_in[20];
    const float* eb2  = (const float*)d_in[21];
    const float* pW1  = (const float*)d_in[22];
    const float* pb1  = (const float*)d_in[23];
    const float* p1g  = (const float*)d_in[24];
    const float* p1b  = (const float*)d_in[25];
    const float* p1m  = (const float*)d_in[26];
    const float* p1v  = (const float*)d_in[27];
    const float* pW2  = (const float*)d_in[28];
    const float* pb2  = (const float*)d_in[29];
    const float* p2g  = (const float*)d_in[30];
    const float* p2b  = (const float*)d_in[31];
    const float* p2m  = (const float*)d_in[32];
    const float* p2v  = (const float*)d_in[33];
    const float* pW3  = (const float*)d_in[34];
    const float* pb3  = (const float*)d_in[35];
    float* out = (float*)d_out;

    char* wk = (char*)d_ws;
    auto carve = [&](size_t bytes) {
        char* p = wk;
        wk += (bytes + 255) & ~(size_t)255;
        return p;
    };
    unsigned*  deg    = (unsigned*)carve((size_t)Nn * 4);
    int*       rowptr = (int*)carve((size_t)(Nn + 1) * 4);
    int*       cursor = (int*)carve((size_t)Nn * 4);
    int*       elist  = (int*)carve((size_t)Ee * 4);
    unsigned*  escan  = (unsigned*)carve((size_t)Nn * 4);
    unsigned*  bsum   = (unsigned*)carve(128 * 4);
    unsigned*  boff   = (unsigned*)carve(128 * 4);
    _Float16*  w16    = (_Float16*)carve((size_t)W16_TOTAL * 2);
    float*     bnA    = (float*)carve((size_t)BN_TOTAL * 4);
    _Float16*  bufX   = (_Float16*)carve((size_t)Nn * 128 * 2);  // x16; later y|z
    _Float16*  bufA   = (_Float16*)carve((size_t)Nn * 128 * 2);  // agg1 out; later aggY
    _Float16*  bufH   = (_Float16*)carve((size_t)Nn * 128 * 2);  // h
    _Float16*  bufY   = bufX;
    _Float16*  bufZ   = bufX + (size_t)Nn * 64;
    _Float16*  bufAy  = bufA;

    const int* e_src = eidx;
    const int* e_dst = eidx + Ee;
    const int SBLK = (Nn + 1023) / 1024;   // 98

    hipMemsetAsync(deg, 0, (size_t)Nn * 4, stream);
    prep_kernel<<<800, 256, 0, stream>>>(x, s1Wl, s1Wr, s2Wl, s2Wr, pW1, eW1, eW2, pW2,
                                         eb1, ebng, ebnb, ebnm, ebnv, eb2,
                                         pb1, p1g, p1b, p1m, p1v,
                                         pb2, p2g, p2b, p2m, p2v, pW3,
                                         w16, bnA, bufX);
    hist_kernel<<<(Ee + 255) / 256, 256, 0, stream>>>(e_dst, deg);
    scanA_kernel<<<SBLK, 1024, 0, stream>>>(deg, escan, bsum);
    scanB_kernel<<<1, 128, 0, stream>>>(bsum, boff, SBLK);
    scanC_kernel<<<SBLK, 1024, 0, stream>>>(escan, boff, rowptr, cursor);
    scatter_kernel<<<(Ee + 255) / 256, 256, 0, stream>>>(e_src, e_dst, cursor, elist);

    // SAGE layer 1
    aggregate16_kernel<128><<<Nn / 4, 256, 0, stream>>>(bufX, rowptr, elist, bufA);
    dense1_kernel<<<(Nn + 63) / 64, 256, 0, stream>>>(
        bufA, bufX, w16 + oW1l, w16 + oW1r, s1bl, bn1g, bn1b, bn1m, bn1v, bufH);

    // SAGE layer 2 (linear commutes with mean)
    gemmY_kernel<<<(Nn + 63) / 64, 256, 0, stream>>>(bufH, w16 + oW2l, bufY);
    aggregate16_kernel<64><<<Nn / 4, 256, 0, stream>>>(bufY, rowptr, elist, bufAy);
    dense2b_kernel<<<(Nn + 63) / 64, 256, 0, stream>>>(
        bufAy, bufH, w16 + oW2r, s2bl, bufZ);

    // fused per-edge predictor (persistent, swapped-operand MFMA)
    edge_kernel<<<EGRID, 512, 0, stream>>>(pe, ef, bufZ, w16, bnA, pb3, out);
}